// Round 16
// baseline (959.544 us; speedup 1.0000x reference)
//
#include <hip/hip_runtime.h>
#include <hip/hip_cooperative_groups.h>
#include <math.h>

namespace cg = cooperative_groups;

#define DD 512
#define NBLKA 400

#define PM 128          // prefilter tile rows
#define PN 256          // prefilter tile cols
#define KB 32           // k-chunk (one MFMA K-step, 32 fp8 elems = 32 B), 16 chunks
#define CSPLIT 6        // column splits of 40 col-tiles -> 480 blocks = 2/CU
#define NC 16           // candidates kept per row per split (fp8 safety, >= k=9)
#define PBUF 32         // push buffer per row
#define PBSTRIDE 36     // 36 floats -> 144B rows, 16B aligned
#define NCTOT (CSPLIT*NC)   // 96 candidates per row total
#define KOUTMAX 16
#define RS_MARGIN 3e-3f     // static rescore cut margin (>= 2x fp8 score err bound)
#define DYN_MARGIN 1.5e-3f  // dynamic cut margin (>= 1x fp8 score err bound)
#define FP8SCALE 32.f       // pre-quantization scale (dodges e4m3 subnormals)
#define INVS2 (1.f/512.f)   // 2/(FP8SCALE^2): score = sqi+sqj - g*INVS2

typedef __attribute__((ext_vector_type(4))) float f32x4;    // MFMA 16x16 accumulator

static __device__ __forceinline__ unsigned char f2e4m3(float f) {
    // RTNE float -> fp8 e4m3fn (OCP). Inputs here are |f| < ~4, no NaN.
    unsigned u = __float_as_uint(f);
    unsigned sgn = (u >> 24) & 0x80;
    int e = (int)((u >> 23) & 0xff);
    unsigned m = u & 0x7fffff;
    int te = e - 120;                         // e4m3 exponent (bias 7)
    unsigned r;
    if (te >= 1) {
        unsigned mm   = m >> 20;              // top 3 mantissa bits
        unsigned rest = m & 0xfffff;
        if (rest > 0x80000 || (rest == 0x80000 && (mm & 1))) ++mm;
        if (mm == 8) { mm = 0; ++te; }
        if (te > 15 || (te == 15 && mm == 7)) r = 0x7e;   // clamp to 448
        else r = (unsigned)((te << 3) | mm);
    } else {
        int sh = 1 - te;                      // subnormal shift
        if (sh > 24 || e == 0) r = 0;
        else {
            unsigned full = m | 0x800000;
            int sa = 20 + sh;                 // <= 44; clamp for shift safety
            if (sa > 31) r = 0;
            else {
                unsigned shifted = full >> sa;
                unsigned rem  = full & ((1u << sa) - 1);
                unsigned half = 1u << (sa - 1);
                if (rem > half || (rem == half && (shifted & 1))) ++shifted;
                r = shifted;                  // carry into exp=1 encodes correctly
            }
        }
    }
    return (unsigned char)(r | sgn);
}

// ---------------- Fused pre-kernel (cooperative): colsum -> colnorm -> row_sq+fp8 ----------------
__global__ __launch_bounds__(256) void prekernel(
    const float* __restrict__ x, double* __restrict__ partial,
    double* __restrict__ rn, double* __restrict__ w,
    double* __restrict__ sq, float* __restrict__ sqf,
    unsigned char* __restrict__ xnbf8, int N, int rows_per_block, int nblk)
{
    cg::grid_group grid = cg::this_grid();
    const int t = threadIdx.x;

    // ---- phase 1: partial column sums of x^2 (fp64, deterministic order) ----
    {
        int b  = blockIdx.x;
        int r0 = b * rows_per_block;
        int r1 = min(r0 + rows_per_block, N);
        double s0 = 0.0, s1 = 0.0;
        for (int r = r0; r < r1; ++r) {
            float v0 = x[(size_t)r * DD + t];
            float v1 = x[(size_t)r * DD + t + 256];
            s0 += (double)v0 * (double)v0;
            s1 += (double)v1 * (double)v1;
        }
        partial[(size_t)b * DD + t]       = s0;
        partial[(size_t)b * DD + t + 256] = s1;
    }
    grid.sync();

    // ---- phase 2: finish column norms; blocks 0..255 handle 2 cols each ----
    __shared__ double red[256];
    if (blockIdx.x < 256) {
#pragma unroll 1
        for (int cc = 0; cc < 2; ++cc) {
            int c = blockIdx.x * 2 + cc;
            double s = 0.0;
            for (int b = t; b < nblk; b += 256) s += partial[(size_t)b * DD + c];
            red[t] = s;
            __syncthreads();
            for (int off = 128; off > 0; off >>= 1) {
                if (t < off) red[t] += red[t + off];
                __syncthreads();
            }
            if (t == 0) {
                double n = fmax(sqrt(red[0]), 1e-12);
                double r = 1.0 / n;
                rn[c] = r;
                w[c]  = r * r;
            }
            __syncthreads();
        }
    }
    grid.sync();

    // ---- phase 3: row_sq + fp8 quantize (scale 32), 1 wave/row grid-strided ----
    {
        int lane   = t & 63;
        int gwave  = (blockIdx.x * blockDim.x + t) >> 6;
        int nwaves = (gridDim.x * blockDim.x) >> 6;
        const double2* rp = (const double2*)rn;
        double2 r0a = rp[lane * 2],       r0b = rp[lane * 2 + 1];
        double2 r1a = rp[128 + lane * 2], r1b = rp[128 + lane * 2 + 1];
        for (int i = gwave; i < N; i += nwaves) {
            const float4* xr = (const float4*)(x + (size_t)i * DD);
            float4 v0 = xr[lane];
            float4 v1 = xr[64 + lane];
            double a0 = (double)v0.x * r0a.x, a1 = (double)v0.y * r0a.y;
            double a2 = (double)v0.z * r0b.x, a3 = (double)v0.w * r0b.y;
            double b0 = (double)v1.x * r1a.x, b1 = (double)v1.y * r1a.y;
            double b2 = (double)v1.z * r1b.x, b3 = (double)v1.w * r1b.y;
            uchar4 c0 = { f2e4m3(FP8SCALE * (float)a0), f2e4m3(FP8SCALE * (float)a1),
                          f2e4m3(FP8SCALE * (float)a2), f2e4m3(FP8SCALE * (float)a3) };
            uchar4 c1 = { f2e4m3(FP8SCALE * (float)b0), f2e4m3(FP8SCALE * (float)b1),
                          f2e4m3(FP8SCALE * (float)b2), f2e4m3(FP8SCALE * (float)b3) };
            *(uchar4*)(xnbf8 + (size_t)i * DD + lane * 4)       = c0;
            *(uchar4*)(xnbf8 + (size_t)i * DD + 256 + lane * 4) = c1;
            double loc = a0*a0 + a1*a1 + a2*a2 + a3*a3 + b0*b0 + b1*b1 + b2*b2 + b3*b3;
#pragma unroll
            for (int off = 32; off > 0; off >>= 1)
                loc += __shfl_xor(loc, off, 64);
            if (lane == 0) { sq[i] = loc; sqf[i] = (float)loc; }
        }
    }
}

// ---------------- Kernel C: fp8 MFMA prefilter, 128x256 tile ----------------
// R16 = R15 resubmitted byte-identical (R15 hit the container-level infra
// failure; same signature as R8/R12 which both passed on identical resubmit).
// Staged bytes halve (fp8): 1.2 GB -> 0.6 GB under the measured ~5 GB/ms
// cooperative-staging law. Same chunk cadence (16x16x32_fp8_fp8, K=32 = 32B
// rows). 3 DMA/thread/chunk -> counted vmcnt(3). 16B-granule XOR swizzle at
// c^(row&1) (2 granules/row). Selection: R11 protocol verbatim, NC=16
// (fp8 candidate-safety). LDS ~64KB, no aliasing (staging only 24KB).
__global__ __launch_bounds__(256, 2) void gemm_prefilter(
    const unsigned char* __restrict__ xnbf8,
    const float* __restrict__ sqf, int* __restrict__ cand, float* __restrict__ cands,
    int N, int ntileM, int ntileN)
{
    // 2 chunk buffers x 12KB: buffer b @ b*12288 {A 4KB (128r x 32B) | B 8KB @ +4096 (256r x 32B)}
    __shared__ __align__(16) unsigned char lds_raw[24576];
    __shared__ __align__(16) float Bsc[PM][PBSTRIDE];   // 18432 B
    __shared__ __align__(16) int   Bid[PM][PBSTRIDE];   // 18432 B
    __shared__ float sqi_s[PM];
    __shared__ float sqj_s[PN];
    __shared__ float thr_s[PM];
    __shared__ int   cnt_s[PM];
    __shared__ int   flag_s;                      // ~64 KB total -> 2 blocks/CU

    const int bid   = blockIdx.x;
    const int q     = bid & 7;
    const int s     = bid >> 3;
    const int ridx  = s / CSPLIT;
    const int split = s - ridx * CSPLIT;
    const int rowb  = q + 8 * ridx;
    if (rowb >= ntileM) return;                   // uniform early exit (pad blocks)
    const int row0  = rowb * PM;

    const int t      = threadIdx.x;
    const int lane15 = t & 15;
    const int quad   = (t >> 4) & 3;
    const int wave   = t >> 6;
    const int wr     = (wave >> 1) * 64;          // row half (0/64)
    const int wc     = (wave & 1) * 128;          // col half (0/128)
    const int ag     = quad >> 1;                 // k-granule (16B) within 32B row
    const int asub   = (quad & 1) * 8;            // byte offset within granule

    if (t == 0) flag_s = 0;
    if (t < PM) {
        int i = row0 + t;
        sqi_s[t] = (i < N) ? sqf[i] : 0.f;
        thr_s[t] = __builtin_inff();
        cnt_s[t] = 0;
    }

    // register-resident running top-NC list for row (row0 + t), t < PM
    float ls[NC];
    int   li[NC];
#pragma unroll
    for (int m = 0; m < NC; ++m) { ls[m] = __builtin_inff(); li[m] = 0x7fffffff; }

    f32x4 acc[4][8];                              // [mt][nt] -- 128 VGPRs

    for (int tile = split; tile < ntileN; tile += CSPLIT) {
        int col0 = tile * PN;

        {   // sqj fill: all 256 threads cover the 256 columns
            int j = col0 + t;
            sqj_s[t] = (j < N) ? sqf[j] : __builtin_inff();
        }
        __syncthreads();   // sqj visible + prior selection's Bsc/Bid accesses done

#pragma unroll
        for (int mt = 0; mt < 4; ++mt)
#pragma unroll
            for (int nt = 0; nt < 8; ++nt)
                acc[mt][nt] = (f32x4){0.f, 0.f, 0.f, 0.f};

        // cooperative DMA of one KB=32 chunk: A 256 granules + B 512 granules
        // = 3 DMA instrs/thread. 16B-granule XOR swizzle c^=(row&1).
        auto STAGE = [&](int kc, int buf) {
            unsigned char* base = lds_raw + (size_t)buf * 12288;
            {   // A region: 256 granules (1/thread)
                int e   = t;
                int row = e >> 1;
                int c   = (e & 1) ^ (row & 1);
                size_t g = (size_t)(row0 + row) * DD + kc + c * 16;
                __builtin_amdgcn_global_load_lds(
                    (const unsigned int*)(xnbf8 + g),
                    (unsigned int*)(base + (size_t)e * 16), 16, 0, 0);
            }
#pragma unroll
            for (int l = 0; l < 2; ++l) {         // B region: 512 granules
                int e   = t + l * 256;
                int row = e >> 1;
                int c   = (e & 1) ^ (row & 1);
                size_t g = (size_t)(col0 + row) * DD + kc + c * 16;
                __builtin_amdgcn_global_load_lds(
                    (const unsigned int*)(xnbf8 + g),
                    (unsigned int*)(base + 4096 + (size_t)e * 16), 16, 0, 0);
            }
        };

        STAGE(0, 0);                               // prologue prefetch (3 units)
#pragma unroll 1
        for (int cc = 0; cc < 16; ++cc) {
            if (cc < 15) {
                STAGE((cc + 1) * KB, (cc + 1) & 1);      // +3 -> 6 outstanding
                __builtin_amdgcn_sched_barrier(0);
                asm volatile("s_waitcnt vmcnt(3)" ::: "memory");  // retire chunk cc
            } else {
                __builtin_amdgcn_sched_barrier(0);
                asm volatile("s_waitcnt vmcnt(0)" ::: "memory");
            }
            __builtin_amdgcn_s_barrier();          // all waves' chunk-cc parts landed
            __builtin_amdgcn_sched_barrier(0);

            const unsigned char* rb = lds_raw + (size_t)(cc & 1) * 12288;
            long af[4], bfg[8];
#pragma unroll
            for (int mt = 0; mt < 4; ++mt) {
                int row = wr + mt * 16 + lane15;
                af[mt] = *(const long*)(rb + (size_t)row * 32 + (size_t)(ag ^ (row & 1)) * 16 + asub);
            }
#pragma unroll
            for (int nt = 0; nt < 8; ++nt) {
                int row = wc + nt * 16 + lane15;
                bfg[nt] = *(const long*)(rb + 4096 + (size_t)row * 32 + (size_t)(ag ^ (row & 1)) * 16 + asub);
            }
#pragma unroll
            for (int mt = 0; mt < 4; ++mt)
#pragma unroll
                for (int nt = 0; nt < 8; ++nt)
                    acc[mt][nt] = __builtin_amdgcn_mfma_f32_16x16x32_fp8_fp8(
                        af[mt], bfg[nt], acc[mt][nt], 0, 0, 0);
            __builtin_amdgcn_sched_barrier(0);
            __builtin_amdgcn_s_barrier();          // reads done before buf re-staged
        }

        // epilogue: scores  s = sqi + sqj - g/512  (g = 1024*dot from scale 32)
#pragma unroll
        for (int mt = 0; mt < 4; ++mt)
#pragma unroll
            for (int nt = 0; nt < 8; ++nt)
#pragma unroll
                for (int reg = 0; reg < 4; ++reg) {
                    int rl = wr + mt * 16 + quad * 4 + reg;
                    int cl = wc + nt * 16 + lane15;
                    float g = acc[mt][nt][reg];
                    acc[mt][nt][reg] = fmaf(-INVS2, g, sqi_s[rl] + sqj_s[cl]);
                }
        __syncthreads();   // all k-loops done before pushes

        // push/merge rounds: R5 protocol, two 64-bit done masks (nt halves)
        bool tile_edge = (col0 + PN > N);
        unsigned long long done0 = 0ull, done1 = 0ull;
        for (;;) {
#pragma unroll
            for (int hn = 0; hn < 2; ++hn) {
#pragma unroll
                for (int mt = 0; mt < 4; ++mt)
#pragma unroll
                    for (int reg = 0; reg < 4; ++reg) {
                        const unsigned long long gb =
                            (0x1111ull << reg) << (mt * 16);
                        unsigned long long dn = hn ? done1 : done0;
                        int rl = wr + mt * 16 + quad * 4 + reg;
                        float th = thr_s[rl];
                        float gmin = fminf(
                            fminf(acc[mt][hn * 4 + 0][reg], acc[mt][hn * 4 + 1][reg]),
                            fminf(acc[mt][hn * 4 + 2][reg], acc[mt][hn * 4 + 3][reg]));
                        if (!tile_edge && gmin > th) {
                            if (hn) done1 |= gb; else done0 |= gb;
                            continue;
                        }
                        if ((dn & gb) == gb) continue;
#pragma unroll
                        for (int u = 0; u < 4; ++u) {
                            const unsigned long long bit = 1ull << (mt * 16 + u * 4 + reg);
                            if (!(dn & bit)) {
                                float sv = acc[mt][hn * 4 + u][reg];
                                int   j  = col0 + wc + (hn * 4 + u) * 16 + lane15;
                                bool ok = false;
                                if (j < N && sv <= th) {
                                    int pos = atomicAdd(&cnt_s[rl], 1);
                                    if (pos < PBUF) {
                                        Bsc[rl][pos] = sv;
                                        Bid[rl][pos] = j;
                                        ok = true;
                                    }
                                } else {
                                    ok = true;
                                }
                                if (ok) { if (hn) done1 |= bit; else done0 |= bit; }
                            }
                        }
                    }
            }
            if (done0 != ~0ull || done1 != ~0ull) flag_s = 1;
            __syncthreads();                 // B1
            if (t < PM) {
                int c = cnt_s[t];
                if (c > PBUF) c = PBUF;
                cnt_s[t] = 0;
                for (int m0 = 0; m0 < c; m0 += 4) {
                    float4 s4 = *(const float4*)&Bsc[t][m0];
                    int4   j4 = *(const int4*)&Bid[t][m0];
#pragma unroll
                    for (int e = 0; e < 4; ++e) {
                        if (m0 + e >= c) break;
                        float sv = (e == 0) ? s4.x : (e == 1) ? s4.y : (e == 2) ? s4.z : s4.w;
                        int   j  = (e == 0) ? j4.x : (e == 1) ? j4.y : (e == 2) ? j4.z : j4.w;
                        if (sv < ls[NC - 1] || (sv == ls[NC - 1] && j < li[NC - 1])) {
                            float cs = sv; int cj = j;
#pragma unroll
                            for (int p = 0; p < NC; ++p) {
                                bool lt = (cs < ls[p]) || (cs == ls[p] && cj < li[p]);
                                float ts = ls[p]; int tj = li[p];
                                if (lt) { ls[p] = cs; li[p] = cj; cs = ts; cj = tj; }
                            }
                        }
                    }
                }
                thr_s[t] = ls[NC - 1];
            }
            __syncthreads();                 // B2
            int go = flag_s;
            __syncthreads();                 // B3
            if (t == 0) flag_s = 0;
            __syncthreads();                 // B4
            if (!go) break;
        }
    }
    // write this split's candidates (index + fp32 score) straight from registers
    if (t < PM) {
        int i = row0 + t;
        if (i < N) {
#pragma unroll
            for (int m = 0; m < NC; ++m) {
                cand [(size_t)i * NCTOT + split * NC + m] = li[m];
                cands[(size_t)i * NCTOT + split * NC + m] = ls[m];
            }
        }
    }
}

// ---------------- Kernel D: pruned exact fp64 rescore + top-k ----------------
// Static pivot cut (9th-smallest prefilter + RS_MARGIN) AND dynamic cut
// (current exact 9th-best + DYN_MARGIN) -- the dynamic cut tightens as exact
// scores accumulate, bounding fp8-margin survivor inflation.
__global__ __launch_bounds__(256) void rescore_topk(
    const float* __restrict__ x, const double* __restrict__ w,
    const double* __restrict__ sq, const int* __restrict__ cand,
    const float* __restrict__ cands, int* __restrict__ out, int N, int k)
{
    __shared__ float Ssc[4][NCTOT];
    int lane = threadIdx.x & 63;
    int wid  = threadIdx.x >> 6;
    int i = blockIdx.x * 4 + wid;
    if (i >= N) return;

    size_t base = (size_t)i * NCTOT;
    Ssc[wid][lane] = cands[base + lane];
    if (lane < NCTOT - 64) Ssc[wid][64 + lane] = cands[base + 64 + lane];

    // 9th-smallest via pivot counting: pivots cover all 96 slots
    float p0 = Ssc[wid][lane];
    float p1 = Ssc[wid][64 + (lane & 31)];
    int c0 = 0, c1 = 0;
    for (int m = 0; m < NCTOT; ++m) {
        float s = Ssc[wid][m];
        c0 += (s <= p0); c1 += (s <= p1);
    }
    float best = __builtin_inff();
    if (c0 >= k) best = p0;
    if (c1 >= k && p1 < best) best = p1;
#pragma unroll
    for (int off = 32; off > 0; off >>= 1)
        best = fminf(best, __shfl_xor(best, off, 64));
    float cut = best + RS_MARGIN;

    double aw[8];
#pragma unroll
    for (int c = 0; c < 8; ++c) {
        int d = lane + 64 * c;
        aw[c] = (double)x[(size_t)i * DD + d] * w[d];
    }
    double sqi = sq[i];

    double bs[KOUTMAX];
    int    bj[KOUTMAX];
    for (int r = 0; r < k; ++r) { bs[r] = __builtin_inf(); bj[r] = 0x7fffffff; }

    int pend = -1;                    // wave-uniform pending candidate index j
    for (int m = 0; m <= NCTOT; ++m) {
        int j1cand = -1;
        if (m < NCTOT) {
            float dcut = fminf(cut, (float)bs[k - 1] + DYN_MARGIN);
            if (Ssc[wid][m] > dcut) continue;         // wave-uniform skip
            j1cand = cand[base + m];
            if (pend < 0) { pend = j1cand; continue; } // buffer first of a pair
        } else if (pend < 0) {
            break;                                     // nothing left
        }
        int j0 = pend, j1 = j1cand;
        pend = -1;
        const float* q0 = &x[(size_t)j0 * DD + lane];
        const float* q1 = (j1 >= 0) ? &x[(size_t)j1 * DD + lane] : q0;
        float v0[8], v1[8];
#pragma unroll
        for (int c = 0; c < 8; ++c) v0[c] = q0[64 * c];
#pragma unroll
        for (int c = 0; c < 8; ++c) v1[c] = q1[64 * c];
        double d0 = 0.0, d1 = 0.0;
#pragma unroll
        for (int c = 0; c < 8; ++c) d0 = fma(aw[c], (double)v0[c], d0);
#pragma unroll
        for (int c = 0; c < 8; ++c) d1 = fma(aw[c], (double)v1[c], d1);
#pragma unroll
        for (int off = 32; off > 0; off >>= 1) {
            d0 += __shfl_xor(d0, off, 64);
            d1 += __shfl_xor(d1, off, 64);
        }
        double s0 = (sqi - 2.0 * d0) + sq[j0];
        double s1 = (j1 >= 0) ? (sqi - 2.0 * d1) + sq[j1] : __builtin_inf();
#pragma unroll 1
        for (int pick = 0; pick < 2; ++pick) {
            double sv = pick ? s1 : s0;
            int    j  = pick ? j1 : j0;
            if (j < 0) continue;
            if (sv < bs[k - 1] || (sv == bs[k - 1] && j < bj[k - 1])) {
                int pos = k - 1;
                while (pos > 0) {
                    double ps = bs[pos - 1]; int pj = bj[pos - 1];
                    if (!(sv < ps || (sv == ps && j < pj))) break;
                    bs[pos] = ps; bj[pos] = pj;
                    --pos;
                }
                bs[pos] = sv; bj[pos] = j;
            }
        }
    }
    if (lane == 0) {
        for (int r = 0; r < k; ++r) {
            out[(size_t)i * k + r]                 = bj[r];
            out[(size_t)N * k + (size_t)i * k + r] = i;
        }
    }
}

extern "C" void kernel_launch(void* const* d_in, const int* in_sizes, int n_in,
                              void* d_out, int out_size, void* d_ws, size_t ws_size,
                              hipStream_t stream) {
    const float* x = (const float*)d_in[0];
    int N = in_sizes[0] / DD;            // 10000
    int k = out_size / (2 * N);          // 9
    if (k > KOUTMAX) k = KOUTMAX;

    char* ws = (char*)d_ws;
    double*        partial = (double*)ws;                       // 400*512*8 = 1638400 B
    double*        rn      = (double*)(ws + 1638400);           // 4096 B
    double*        w       = (double*)(ws + 1642496);           // 4096 B
    double*        sq      = (double*)(ws + 1646592);           // 80000 B
    float*         sqf     = (float*) (ws + 1726592);           // 40000 B
    unsigned char* xnbf8   = (unsigned char*)(ws + 1766592);    // N*512 = 5.12 MB
    int*           cand    = (int*)   (ws + 6886592);           // N*96*4 = 3.84 MB
    float*         cands   = (float*) (ws + 10726592);          // N*96*4 = 3.84 MB -> end 14.57 MB

    int rpb  = (N + NBLKA - 1) / NBLKA;
    int nblk = NBLKA;
    void* pre_args[] = { (void*)&x, (void*)&partial, (void*)&rn, (void*)&w,
                         (void*)&sq, (void*)&sqf, (void*)&xnbf8,
                         (void*)&N, (void*)&rpb, (void*)&nblk };
    hipLaunchCooperativeKernel((const void*)prekernel, dim3(NBLKA), dim3(256),
                               pre_args, 0, stream);

    int ntileM = (N + PM - 1) / PM;      // 79 row-tiles of 128
    int ntileN = (N + PN - 1) / PN;      // 40 col-tiles of 256
    int rows_per_xcd = (ntileM + 7) / 8; // 10
    int nblkc = 8 * rows_per_xcd * CSPLIT; // 480 (pad blocks exit early)
    hipLaunchKernelGGL(gemm_prefilter, dim3(nblkc), dim3(256), 0, stream,
                       xnbf8, sqf, cand, cands, N, ntileM, ntileN);

    hipLaunchKernelGGL(rescore_topk, dim3((N + 3) / 4), dim3(256), 0, stream,
                       x, w, sq, cand, cands, (int*)d_out, N, k);
}

// Round 17
// 669.907 us; speedup vs baseline: 1.4324x; 1.4324x over previous
//
#include <hip/hip_runtime.h>
#include <hip/hip_cooperative_groups.h>
#include <math.h>

namespace cg = cooperative_groups;

#define DD 512
#define NBLKA 400

#define PM 128          // prefilter tile rows
#define PN 256          // prefilter tile cols (R11/R14 config: best measured)
#define KB 32           // k-chunk (one MFMA K-step), 16 chunks/tile
#define CSPLIT 6        // column splits of 40 col-tiles -> 480 blocks = 2/CU
#define NC 12           // candidates kept per row per split (>= k=9)
#define PBUF 32         // push buffer per row
#define PBSTRIDE 36     // 36 floats -> 144B rows, 16B aligned
#define NCTOT (CSPLIT*NC)   // 72 candidates per row total
#define KOUTMAX 16
#define RS_MARGIN 2e-4f     // rescore prune margin (bf16 score err bound ~3e-5)

typedef __attribute__((ext_vector_type(8))) short bf16x8;   // 8 bf16 = 4 VGPR
typedef __attribute__((ext_vector_type(4))) float f32x4;    // MFMA 16x16 accumulator

static __device__ __forceinline__ unsigned short f2bf(float f) {
    unsigned u = __float_as_uint(f);
    u += 0x7fff + ((u >> 16) & 1);      // round-to-nearest-even
    return (unsigned short)(u >> 16);
}

// ---------------- Fused pre-kernel (cooperative): colsum -> colnorm -> row_sq ----------------
__global__ __launch_bounds__(256) void prekernel(
    const float* __restrict__ x, double* __restrict__ partial,
    double* __restrict__ rn, double* __restrict__ w,
    double* __restrict__ sq, float* __restrict__ sqf,
    unsigned short* __restrict__ xnbf, int N, int rows_per_block, int nblk)
{
    cg::grid_group grid = cg::this_grid();
    const int t = threadIdx.x;

    // ---- phase 1: partial column sums of x^2 (fp64, deterministic order) ----
    {
        int b  = blockIdx.x;
        int r0 = b * rows_per_block;
        int r1 = min(r0 + rows_per_block, N);
        double s0 = 0.0, s1 = 0.0;
        for (int r = r0; r < r1; ++r) {
            float v0 = x[(size_t)r * DD + t];
            float v1 = x[(size_t)r * DD + t + 256];
            s0 += (double)v0 * (double)v0;
            s1 += (double)v1 * (double)v1;
        }
        partial[(size_t)b * DD + t]       = s0;
        partial[(size_t)b * DD + t + 256] = s1;
    }
    grid.sync();

    // ---- phase 2: finish column norms; blocks 0..255 handle 2 cols each ----
    __shared__ double red[256];
    if (blockIdx.x < 256) {
#pragma unroll 1
        for (int cc = 0; cc < 2; ++cc) {
            int c = blockIdx.x * 2 + cc;
            double s = 0.0;
            for (int b = t; b < nblk; b += 256) s += partial[(size_t)b * DD + c];
            red[t] = s;
            __syncthreads();
            for (int off = 128; off > 0; off >>= 1) {
                if (t < off) red[t] += red[t + off];
                __syncthreads();
            }
            if (t == 0) {
                double n = fmax(sqrt(red[0]), 1e-12);
                double r = 1.0 / n;
                rn[c] = r;
                w[c]  = r * r;
            }
            __syncthreads();
        }
    }
    grid.sync();

    // ---- phase 3: row_sq, 1 wave per row, grid-strided ----
    {
        int lane   = t & 63;
        int gwave  = (blockIdx.x * blockDim.x + t) >> 6;
        int nwaves = (gridDim.x * blockDim.x) >> 6;
        const double2* rp = (const double2*)rn;
        double2 r0a = rp[lane * 2],       r0b = rp[lane * 2 + 1];
        double2 r1a = rp[128 + lane * 2], r1b = rp[128 + lane * 2 + 1];
        for (int i = gwave; i < N; i += nwaves) {
            const float4* xr = (const float4*)(x + (size_t)i * DD);
            float4 v0 = xr[lane];
            float4 v1 = xr[64 + lane];
            double a0 = (double)v0.x * r0a.x, a1 = (double)v0.y * r0a.y;
            double a2 = (double)v0.z * r0b.x, a3 = (double)v0.w * r0b.y;
            double b0 = (double)v1.x * r1a.x, b1 = (double)v1.y * r1a.y;
            double b2 = (double)v1.z * r1b.x, b3 = (double)v1.w * r1b.y;
            ushort4 s0 = { f2bf((float)a0), f2bf((float)a1), f2bf((float)a2), f2bf((float)a3) };
            ushort4 s1 = { f2bf((float)b0), f2bf((float)b1), f2bf((float)b2), f2bf((float)b3) };
            *(ushort4*)(xnbf + (size_t)i * DD + lane * 4)       = s0;
            *(ushort4*)(xnbf + (size_t)i * DD + 256 + lane * 4) = s1;
            double loc = a0*a0 + a1*a1 + a2*a2 + a3*a3 + b0*b0 + b1*b1 + b2*b2 + b3*b3;
#pragma unroll
            for (int off = 32; off > 0; off >>= 1)
                loc += __shfl_xor(loc, off, 64);
            if (lane == 0) { sq[i] = loc; sqf[i] = (float)loc; }
        }
    }
}

// ---------------- Kernel C: bf16 MFMA prefilter, 128x256 tile + tile-1 min-seed ----------------
// R17 = R14 gemm + min-seed round on each block's FIRST tile: thr=inf there
// forced all 256 scores/row through the PBUF=32 buffer -> 8 push/merge
// rounds (~6us each, from R1's PBUF ablation). Seed round: each of the 32
// threads holding a row pushes only its per-row minimum (32 = PBUF exactly);
// merged 12th-of-mins is a valid (monotone-decreasing) threshold ~= 40th-
// smallest of the row -> main loop needs ~2 rounds instead of 8.
// fp8 experiment (R16) reverted: FETCH halved but conflicts doubled (8B
// ds_read 4-way) and rescore margin inflation cost +190us -- net loss.
__global__ __launch_bounds__(256, 2) void gemm_prefilter(
    const unsigned short* __restrict__ xnbf,
    const float* __restrict__ sqf, int* __restrict__ cand, float* __restrict__ cands,
    int N, int ntileM, int ntileN)
{
    // 2 chunk buffers x 24KB: buffer b @ b*24576 {A 8KB (128r x 64B) | B 16KB @ +8192 (256r x 64B)}
    __shared__ __align__(16) unsigned char lds_raw[49152];
    __shared__ float sqi_s[PM];
    __shared__ float sqj_s[PN];
    __shared__ float thr_s[PM];
    __shared__ int   cnt_s[PM];
    __shared__ int   flag_s;                      // ~51.7 KB total -> 2 blocks/CU

    // push buffers alias the (selection-phase-dead) staging LDS
    float (*Bsc)[PBSTRIDE] = (float (*)[PBSTRIDE]) lds_raw;             // 18432 B in buf0
    int   (*Bid)[PBSTRIDE] = (int   (*)[PBSTRIDE]) (lds_raw + 24576);   // 18432 B in buf1

    const int bid   = blockIdx.x;
    const int q     = bid & 7;
    const int s     = bid >> 3;
    const int ridx  = s / CSPLIT;
    const int split = s - ridx * CSPLIT;
    const int rowb  = q + 8 * ridx;
    if (rowb >= ntileM) return;                   // uniform early exit (pad blocks)
    const int row0  = rowb * PM;

    const int t      = threadIdx.x;
    const int lane15 = t & 15;
    const int quad   = (t >> 4) & 3;
    const int wave   = t >> 6;
    const int wr     = (wave >> 1) * 64;          // row half (0/64)
    const int wc     = (wave & 1) * 128;          // col half (0/128)
    const int sl     = quad ^ (lane15 & 3);       // swizzled k-granule read slot

    if (t == 0) flag_s = 0;
    if (t < PM) {
        int i = row0 + t;
        sqi_s[t] = (i < N) ? sqf[i] : 0.f;
        thr_s[t] = __builtin_inff();
        cnt_s[t] = 0;
    }

    // register-resident running top-NC list for row (row0 + t), t < PM
    float ls[NC];
    int   li[NC];
#pragma unroll
    for (int m = 0; m < NC; ++m) { ls[m] = __builtin_inff(); li[m] = 0x7fffffff; }

    f32x4 acc[4][8];                              // [mt][nt] -- 128 VGPRs

    for (int tile = split; tile < ntileN; tile += CSPLIT) {
        int col0 = tile * PN;

        {   // sqj fill: all 256 threads cover the 256 columns
            int j = col0 + t;
            sqj_s[t] = (j < N) ? sqf[j] : __builtin_inff();
        }
        __syncthreads();   // sqj visible + prior selection's Bsc/Bid accesses done

#pragma unroll
        for (int mt = 0; mt < 4; ++mt)
#pragma unroll
            for (int nt = 0; nt < 8; ++nt)
                acc[mt][nt] = (f32x4){0.f, 0.f, 0.f, 0.f};

        // cooperative DMA of one KB=32 chunk: A 512 granules + B 1024 granules
        // = 6 DMA instrs/thread. 16B-granule XOR swizzle c^=(row&3).
        auto STAGE = [&](int kc, int buf) {
            unsigned char* base = lds_raw + (size_t)buf * 24576;
#pragma unroll
            for (int l = 0; l < 2; ++l) {         // A region: 512 granules
                int e   = t + l * 256;
                int row = e >> 2;
                int c   = (e & 3) ^ (row & 3);
                size_t g = (size_t)(row0 + row) * DD + kc + c * 8;
                __builtin_amdgcn_global_load_lds(
                    (const unsigned int*)(xnbf + g),
                    (unsigned int*)(base + (size_t)e * 16), 16, 0, 0);
            }
#pragma unroll
            for (int l = 0; l < 4; ++l) {         // B region: 1024 granules
                int e   = t + l * 256;
                int row = e >> 2;
                int c   = (e & 3) ^ (row & 3);
                size_t g = (size_t)(col0 + row) * DD + kc + c * 8;
                __builtin_amdgcn_global_load_lds(
                    (const unsigned int*)(xnbf + g),
                    (unsigned int*)(base + 8192 + (size_t)e * 16), 16, 0, 0);
            }
        };

        STAGE(0, 0);                               // prologue prefetch (6 units)
#pragma unroll 1
        for (int cc = 0; cc < 16; ++cc) {
            if (cc < 15) {
                STAGE((cc + 1) * KB, (cc + 1) & 1);      // +6 -> 12 outstanding
                __builtin_amdgcn_sched_barrier(0);
                asm volatile("s_waitcnt vmcnt(6)" ::: "memory");  // retire chunk cc
            } else {
                __builtin_amdgcn_sched_barrier(0);
                asm volatile("s_waitcnt vmcnt(0)" ::: "memory");
            }
            __builtin_amdgcn_s_barrier();          // all waves' chunk-cc parts landed
            __builtin_amdgcn_sched_barrier(0);

            const unsigned char* rb = lds_raw + (size_t)(cc & 1) * 24576;
            bf16x8 af[4], bfg[8];
#pragma unroll
            for (int mt = 0; mt < 4; ++mt)
                af[mt] = *(const bf16x8*)(rb + (size_t)(wr + mt * 16 + lane15) * 64 + sl * 16);
#pragma unroll
            for (int nt = 0; nt < 8; ++nt)
                bfg[nt] = *(const bf16x8*)(rb + 8192 + (size_t)(wc + nt * 16 + lane15) * 64 + sl * 16);
#pragma unroll
            for (int mt = 0; mt < 4; ++mt)
#pragma unroll
                for (int nt = 0; nt < 8; ++nt)
                    acc[mt][nt] = __builtin_amdgcn_mfma_f32_16x16x32_bf16(
                        af[mt], bfg[nt], acc[mt][nt], 0, 0, 0);
            __builtin_amdgcn_sched_barrier(0);
            __builtin_amdgcn_s_barrier();          // reads done before buf re-staged
        }

        // epilogue: scores in place  s = (sq_i - 2g) + sq_j
#pragma unroll
        for (int mt = 0; mt < 4; ++mt)
#pragma unroll
            for (int nt = 0; nt < 8; ++nt)
#pragma unroll
                for (int reg = 0; reg < 4; ++reg) {
                    int rl = wr + mt * 16 + quad * 4 + reg;
                    int cl = wc + nt * 16 + lane15;
                    float g = acc[mt][nt][reg];
                    acc[mt][nt][reg] = (sqi_s[rl] - 2.f * g) + sqj_s[cl];
                }
        __syncthreads();   // all k-loops done before pushes touch the alias

        // merge helper: drain this row's push buffer into the register list
        auto MERGE = [&]() {
            if (t < PM) {
                int c = cnt_s[t];
                if (c > PBUF) c = PBUF;
                cnt_s[t] = 0;
                for (int m0 = 0; m0 < c; m0 += 4) {
                    float4 s4 = *(const float4*)&Bsc[t][m0];
                    int4   j4 = *(const int4*)&Bid[t][m0];
#pragma unroll
                    for (int e = 0; e < 4; ++e) {
                        if (m0 + e >= c) break;
                        float sv = (e == 0) ? s4.x : (e == 1) ? s4.y : (e == 2) ? s4.z : s4.w;
                        int   j  = (e == 0) ? j4.x : (e == 1) ? j4.y : (e == 2) ? j4.z : j4.w;
                        if (sv < ls[NC - 1] || (sv == ls[NC - 1] && j < li[NC - 1])) {
                            float cs = sv; int cj = j;
#pragma unroll
                            for (int p = 0; p < NC; ++p) {
                                bool lt = (cs < ls[p]) || (cs == ls[p] && cj < li[p]);
                                float ts = ls[p]; int tj = li[p];
                                if (lt) { ls[p] = cs; li[p] = cj; cs = ts; cj = tj; }
                            }
                        }
                    }
                }
                thr_s[t] = ls[NC - 1];
            }
        };

        bool tile_edge = (col0 + PN > N);
        unsigned long long done0 = 0ull, done1 = 0ull;

        if (tile == split) {
            // ---- seed round (first tile only; thr is inf): each thread
            // pushes only its per-row minimum -> 32 pushes/row = PBUF. ----
#pragma unroll
            for (int mt = 0; mt < 4; ++mt)
#pragma unroll
                for (int reg = 0; reg < 4; ++reg) {
                    int rl = wr + mt * 16 + quad * 4 + reg;
                    float mn = __builtin_inff(); int bn = -1;
#pragma unroll
                    for (int nt = 0; nt < 8; ++nt) {
                        float sv = acc[mt][nt][reg];
                        int   j  = col0 + wc + nt * 16 + lane15;
                        if (j < N && sv < mn) { mn = sv; bn = nt; }
                    }
                    if (bn >= 0) {
                        int pos = atomicAdd(&cnt_s[rl], 1);
                        if (pos < PBUF) {
                            Bsc[rl][pos] = mn;
                            Bid[rl][pos] = col0 + wc + bn * 16 + lane15;
                            unsigned long long bit =
                                1ull << (mt * 16 + (bn & 3) * 4 + reg);
                            if (bn < 4) done0 |= bit; else done1 |= bit;
                        }
                    } else {
                        // all 8 cols OOB -> whole group done in both masks
                        unsigned long long gb = (0x1111ull << reg) << (mt * 16);
                        done0 |= gb; done1 |= gb;
                    }
                }
            __syncthreads();             // seed pushes visible
            MERGE();                     // thr becomes ~40th-smallest of row
            __syncthreads();             // thr/cnt reset visible
        }

        // push/merge rounds: R5 protocol, two 64-bit done masks (nt halves)
        for (;;) {
#pragma unroll
            for (int hn = 0; hn < 2; ++hn) {
#pragma unroll
                for (int mt = 0; mt < 4; ++mt)
#pragma unroll
                    for (int reg = 0; reg < 4; ++reg) {
                        const unsigned long long gb =
                            (0x1111ull << reg) << (mt * 16);
                        unsigned long long dn = hn ? done1 : done0;
                        int rl = wr + mt * 16 + quad * 4 + reg;
                        float th = thr_s[rl];
                        float gmin = fminf(
                            fminf(acc[mt][hn * 4 + 0][reg], acc[mt][hn * 4 + 1][reg]),
                            fminf(acc[mt][hn * 4 + 2][reg], acc[mt][hn * 4 + 3][reg]));
                        if (!tile_edge && gmin > th) {
                            if (hn) done1 |= gb; else done0 |= gb;
                            continue;
                        }
                        if ((dn & gb) == gb) continue;
#pragma unroll
                        for (int u = 0; u < 4; ++u) {
                            const unsigned long long bit = 1ull << (mt * 16 + u * 4 + reg);
                            if (!(dn & bit)) {
                                float sv = acc[mt][hn * 4 + u][reg];
                                int   j  = col0 + wc + (hn * 4 + u) * 16 + lane15;
                                bool ok = false;
                                if (j < N && sv <= th) {
                                    int pos = atomicAdd(&cnt_s[rl], 1);
                                    if (pos < PBUF) {
                                        Bsc[rl][pos] = sv;
                                        Bid[rl][pos] = j;
                                        ok = true;
                                    }
                                } else {
                                    ok = true;
                                }
                                if (ok) { if (hn) done1 |= bit; else done0 |= bit; }
                            }
                        }
                    }
            }
            if (done0 != ~0ull || done1 != ~0ull) flag_s = 1;
            __syncthreads();                 // B1
            MERGE();
            __syncthreads();                 // B2
            int go = flag_s;
            __syncthreads();                 // B3
            if (t == 0) flag_s = 0;
            __syncthreads();                 // B4
            if (!go) break;
        }
    }
    // write this split's candidates (index + fp32 score) straight from registers
    if (t < PM) {
        int i = row0 + t;
        if (i < N) {
#pragma unroll
            for (int m = 0; m < NC; ++m) {
                cand [(size_t)i * NCTOT + split * NC + m] = li[m];
                cands[(size_t)i * NCTOT + split * NC + m] = ls[m];
            }
        }
    }
}

// ---------------- Kernel D: pruned exact fp64 rescore + top-k (R14 verbatim) ----------------
__global__ __launch_bounds__(256) void rescore_topk(
    const float* __restrict__ x, const double* __restrict__ w,
    const double* __restrict__ sq, const int* __restrict__ cand,
    const float* __restrict__ cands, int* __restrict__ out, int N, int k)
{
    __shared__ float Ssc[4][NCTOT];
    int lane = threadIdx.x & 63;
    int wid  = threadIdx.x >> 6;
    int i = blockIdx.x * 4 + wid;
    if (i >= N) return;

    size_t base = (size_t)i * NCTOT;
    Ssc[wid][lane] = cands[base + lane];
    if (lane < NCTOT - 64) Ssc[wid][64 + lane] = cands[base + 64 + lane];

    // 9th-smallest via pivot counting: pivots cover all 72 slots
    float p0 = Ssc[wid][lane];
    float p1 = Ssc[wid][64 + (lane & 7)];
    int c0 = 0, c1 = 0;
    for (int m = 0; m < NCTOT; ++m) {
        float s = Ssc[wid][m];
        c0 += (s <= p0); c1 += (s <= p1);
    }
    float best = __builtin_inff();
    if (c0 >= k) best = p0;
    if (c1 >= k && p1 < best) best = p1;
#pragma unroll
    for (int off = 32; off > 0; off >>= 1)
        best = fminf(best, __shfl_xor(best, off, 64));
    float cut = best + RS_MARGIN;

    double aw[8];
#pragma unroll
    for (int c = 0; c < 8; ++c) {
        int d = lane + 64 * c;
        aw[c] = (double)x[(size_t)i * DD + d] * w[d];
    }
    double sqi = sq[i];

    double bs[KOUTMAX];
    int    bj[KOUTMAX];
    for (int r = 0; r < k; ++r) { bs[r] = __builtin_inf(); bj[r] = 0x7fffffff; }

    int pend = -1;                    // wave-uniform pending candidate index j
    for (int m = 0; m <= NCTOT; ++m) {
        int j1cand = -1;
        if (m < NCTOT) {
            if (Ssc[wid][m] > cut) continue;          // wave-uniform skip
            j1cand = cand[base + m];
            if (pend < 0) { pend = j1cand; continue; } // buffer first of a pair
        } else if (pend < 0) {
            break;                                     // nothing left
        }
        int j0 = pend, j1 = j1cand;
        pend = -1;
        const float* q0 = &x[(size_t)j0 * DD + lane];
        const float* q1 = (j1 >= 0) ? &x[(size_t)j1 * DD + lane] : q0;
        float v0[8], v1[8];
#pragma unroll
        for (int c = 0; c < 8; ++c) v0[c] = q0[64 * c];
#pragma unroll
        for (int c = 0; c < 8; ++c) v1[c] = q1[64 * c];
        double d0 = 0.0, d1 = 0.0;
#pragma unroll
        for (int c = 0; c < 8; ++c) d0 = fma(aw[c], (double)v0[c], d0);
#pragma unroll
        for (int c = 0; c < 8; ++c) d1 = fma(aw[c], (double)v1[c], d1);
#pragma unroll
        for (int off = 32; off > 0; off >>= 1) {
            d0 += __shfl_xor(d0, off, 64);
            d1 += __shfl_xor(d1, off, 64);
        }
        double s0 = (sqi - 2.0 * d0) + sq[j0];
        double s1 = (j1 >= 0) ? (sqi - 2.0 * d1) + sq[j1] : __builtin_inf();
#pragma unroll 1
        for (int pick = 0; pick < 2; ++pick) {
            double sv = pick ? s1 : s0;
            int    j  = pick ? j1 : j0;
            if (j < 0) continue;
            if (sv < bs[k - 1] || (sv == bs[k - 1] && j < bj[k - 1])) {
                int pos = k - 1;
                while (pos > 0) {
                    double ps = bs[pos - 1]; int pj = bj[pos - 1];
                    if (!(sv < ps || (sv == ps && j < pj))) break;
                    bs[pos] = ps; bj[pos] = pj;
                    --pos;
                }
                bs[pos] = sv; bj[pos] = j;
            }
        }
    }
    if (lane == 0) {
        for (int r = 0; r < k; ++r) {
            out[(size_t)i * k + r]                 = bj[r];
            out[(size_t)N * k + (size_t)i * k + r] = i;
        }
    }
}

extern "C" void kernel_launch(void* const* d_in, const int* in_sizes, int n_in,
                              void* d_out, int out_size, void* d_ws, size_t ws_size,
                              hipStream_t stream) {
    const float* x = (const float*)d_in[0];
    int N = in_sizes[0] / DD;            // 10000
    int k = out_size / (2 * N);          // 9
    if (k > KOUTMAX) k = KOUTMAX;

    char* ws = (char*)d_ws;
    double*         partial = (double*)ws;                       // 400*512*8 = 1638400 B
    double*         rn      = (double*)(ws + 1638400);           // 4096 B
    double*         w       = (double*)(ws + 1642496);           // 4096 B
    double*         sq      = (double*)(ws + 1646592);           // 80000 B
    float*          sqf     = (float*) (ws + 1726592);           // 40000 B
    unsigned short* xnbf    = (unsigned short*)(ws + 1766592);   // N*512*2 = 10.24 MB
    int*            cand    = (int*)   (ws + 12006592);          // N*72*4 = 2.88 MB
    float*          cands   = (float*) (ws + 14886592);          // N*72*4 = 2.88 MB

    int rpb  = (N + NBLKA - 1) / NBLKA;
    int nblk = NBLKA;
    void* pre_args[] = { (void*)&x, (void*)&partial, (void*)&rn, (void*)&w,
                         (void*)&sq, (void*)&sqf, (void*)&xnbf,
                         (void*)&N, (void*)&rpb, (void*)&nblk };
    hipLaunchCooperativeKernel((const void*)prekernel, dim3(NBLKA), dim3(256),
                               pre_args, 0, stream);

    int ntileM = (N + PM - 1) / PM;      // 79 row-tiles of 128
    int ntileN = (N + PN - 1) / PN;      // 40 col-tiles of 256
    int rows_per_xcd = (ntileM + 7) / 8; // 10
    int nblkc = 8 * rows_per_xcd * CSPLIT; // 480 (pad blocks exit early)
    hipLaunchKernelGGL(gemm_prefilter, dim3(nblkc), dim3(256), 0, stream,
                       xnbf, sqf, cand, cands, N, ntileM, ntileN);

    hipLaunchKernelGGL(rescore_topk, dim3((N + 3) / 4), dim3(256), 0, stream,
                       x, w, sq, cand, cands, (int*)d_out, N, k);
}

// Round 18
// 666.770 us; speedup vs baseline: 1.4391x; 1.0047x over previous
//
#include <hip/hip_runtime.h>
#include <hip/hip_cooperative_groups.h>
#include <math.h>

namespace cg = cooperative_groups;

#define DD 512
#define NBLKA 400

#define PM 128          // prefilter tile rows
#define PN 256          // prefilter tile cols
#define KB 32           // k-chunk (one MFMA K-step), 16 chunks/tile
#define CSPLIT 6        // column splits of 40 col-tiles -> 480 blocks = 2/CU
#define NC 12           // candidates kept per row per split (>= k=9)
#define PBUF 32         // push buffer per row
#define PBSTRIDE 36     // 36 floats -> 144B rows, 16B aligned
#define NCTOT (CSPLIT*NC)   // 72 candidates per row total
#define KOUTMAX 16
#define RS_MARGIN 2e-4f     // rescore prune margin (bf16 score err bound ~3e-5)

typedef __attribute__((ext_vector_type(8))) short bf16x8;   // 8 bf16 = 4 VGPR
typedef __attribute__((ext_vector_type(4))) float f32x4;    // MFMA 16x16 accumulator

static __device__ __forceinline__ unsigned short f2bf(float f) {
    unsigned u = __float_as_uint(f);
    u += 0x7fff + ((u >> 16) & 1);      // round-to-nearest-even
    return (unsigned short)(u >> 16);
}

// ---------------- Fused pre-kernel: colsum -> colnorm -> row_sq + TILED bf16 write ----------------
// R18: phase 3 writes A/B operands in the exact LDS image layout the gemm
// stages (per tile, per chunk, granule swizzle slot = g ^ (row&3) PRE-BAKED),
// zero-padded to full tiles. gemm's STAGE then reads contiguous 8/16KB
// streams instead of 16-way-scattered 64B segments (the suspected cause of
// the measured ~15 GB/s/CU cooperative staging cap; R9 showed the pipe does
// >=28 GB/s/CU).
__global__ __launch_bounds__(256) void prekernel(
    const float* __restrict__ x, double* __restrict__ partial,
    double* __restrict__ rn, double* __restrict__ w,
    double* __restrict__ sq, float* __restrict__ sqf,
    unsigned char* __restrict__ Atiled, unsigned char* __restrict__ Btiled,
    int N, int rows_per_block, int nblk, int NpadA, int NpadB)
{
    cg::grid_group grid = cg::this_grid();
    const int t = threadIdx.x;

    // ---- phase 1: partial column sums of x^2 (fp64, deterministic order) ----
    {
        int b  = blockIdx.x;
        int r0 = b * rows_per_block;
        int r1 = min(r0 + rows_per_block, N);
        double s0 = 0.0, s1 = 0.0;
        for (int r = r0; r < r1; ++r) {
            float v0 = x[(size_t)r * DD + t];
            float v1 = x[(size_t)r * DD + t + 256];
            s0 += (double)v0 * (double)v0;
            s1 += (double)v1 * (double)v1;
        }
        partial[(size_t)b * DD + t]       = s0;
        partial[(size_t)b * DD + t + 256] = s1;
    }
    grid.sync();

    // ---- phase 2: finish column norms; blocks 0..255 handle 2 cols each ----
    __shared__ double red[256];
    if (blockIdx.x < 256) {
#pragma unroll 1
        for (int cc = 0; cc < 2; ++cc) {
            int c = blockIdx.x * 2 + cc;
            double s = 0.0;
            for (int b = t; b < nblk; b += 256) s += partial[(size_t)b * DD + c];
            red[t] = s;
            __syncthreads();
            for (int off = 128; off > 0; off >>= 1) {
                if (t < off) red[t] += red[t + off];
                __syncthreads();
            }
            if (t == 0) {
                double n = fmax(sqrt(red[0]), 1e-12);
                double r = 1.0 / n;
                rn[c] = r;
                w[c]  = r * r;
            }
            __syncthreads();
        }
    }
    grid.sync();

    // ---- phase 3: row_sq + tiled bf16 writes, 1 wave/row grid-strided ----
    {
        int lane   = t & 63;
        int gwave  = (blockIdx.x * blockDim.x + t) >> 6;
        int nwaves = (gridDim.x * blockDim.x) >> 6;
        const double2* rp = (const double2*)rn;
        double2 r0a = rp[lane * 2],       r0b = rp[lane * 2 + 1];
        double2 r1a = rp[128 + lane * 2], r1b = rp[128 + lane * 2 + 1];
        // per-lane element halves: le0 covers bytes [8*le0,+8), le1 = le0+64
        const int le0 = lane, le1 = lane + 64;
        const int cc0 = le0 >> 3, gl0 = (le0 & 7) >> 1, hf0 = le0 & 1;
        const int cc1 = le1 >> 3, gl1 = (le1 & 7) >> 1, hf1 = le1 & 1;
        for (int i = gwave; i < NpadB; i += nwaves) {
            ushort4 s0 = {0,0,0,0}, s1 = {0,0,0,0};
            if (i < N) {
                const float4* xr = (const float4*)(x + (size_t)i * DD);
                float4 v0 = xr[lane];
                float4 v1 = xr[64 + lane];
                double a0 = (double)v0.x * r0a.x, a1 = (double)v0.y * r0a.y;
                double a2 = (double)v0.z * r0b.x, a3 = (double)v0.w * r0b.y;
                double b0 = (double)v1.x * r1a.x, b1 = (double)v1.y * r1a.y;
                double b2 = (double)v1.z * r1b.x, b3 = (double)v1.w * r1b.y;
                s0 = (ushort4){ f2bf((float)a0), f2bf((float)a1), f2bf((float)a2), f2bf((float)a3) };
                s1 = (ushort4){ f2bf((float)b0), f2bf((float)b1), f2bf((float)b2), f2bf((float)b3) };
                double loc = a0*a0 + a1*a1 + a2*a2 + a3*a3 + b0*b0 + b1*b1 + b2*b2 + b3*b3;
#pragma unroll
                for (int off = 32; off > 0; off >>= 1)
                    loc += __shfl_xor(loc, off, 64);
                if (lane == 0) { sq[i] = loc; sqf[i] = (float)loc; }
            }
            int sw = i & 3;                        // baked granule swizzle key
            if (i < NpadA) {                       // A tile write (128-row tiles)
                size_t tb = ((size_t)(i >> 7) * 16) * 8192 + (size_t)(i & 127) * 64;
                *(ushort4*)(Atiled + tb + (size_t)cc0 * 8192 + (gl0 ^ sw) * 16 + hf0 * 8) = s0;
                *(ushort4*)(Atiled + tb + (size_t)cc1 * 8192 + (gl1 ^ sw) * 16 + hf1 * 8) = s1;
            }
            {                                      // B tile write (256-row tiles)
                size_t tb = ((size_t)(i >> 8) * 16) * 16384 + (size_t)(i & 255) * 64;
                *(ushort4*)(Btiled + tb + (size_t)cc0 * 16384 + (gl0 ^ sw) * 16 + hf0 * 8) = s0;
                *(ushort4*)(Btiled + tb + (size_t)cc1 * 16384 + (gl1 ^ sw) * 16 + hf1 * 8) = s1;
            }
        }
    }
}

// ---------------- Kernel C: bf16 MFMA prefilter, 128x256 tile, streamed staging + min-seed ----------------
// R18 = R17 with STAGE reading the pre-tiled operands as contiguous streams
// (chunk = one 8KB A block + one 16KB B block, consecutive lanes reading
// consecutive 16B). LDS layout/read addressing identical (swizzle pre-baked).
// Selection: R17's min-seed + 4-barrier protocol, byte-identical.
__global__ __launch_bounds__(256, 2) void gemm_prefilter(
    const unsigned char* __restrict__ Atiled,
    const unsigned char* __restrict__ Btiled,
    const float* __restrict__ sqf, int* __restrict__ cand, float* __restrict__ cands,
    int N, int ntileM, int ntileN)
{
    // 2 chunk buffers x 24KB: buffer b @ b*24576 {A 8KB (128r x 64B) | B 16KB @ +8192 (256r x 64B)}
    __shared__ __align__(16) unsigned char lds_raw[49152];
    __shared__ float sqi_s[PM];
    __shared__ float sqj_s[PN];
    __shared__ float thr_s[PM];
    __shared__ int   cnt_s[PM];
    __shared__ int   flag_s;                      // ~51.7 KB total -> 2 blocks/CU

    // push buffers alias the (selection-phase-dead) staging LDS
    float (*Bsc)[PBSTRIDE] = (float (*)[PBSTRIDE]) lds_raw;             // 18432 B in buf0
    int   (*Bid)[PBSTRIDE] = (int   (*)[PBSTRIDE]) (lds_raw + 24576);   // 18432 B in buf1

    const int bid   = blockIdx.x;
    const int q     = bid & 7;
    const int s     = bid >> 3;
    const int ridx  = s / CSPLIT;
    const int split = s - ridx * CSPLIT;
    const int rowb  = q + 8 * ridx;
    if (rowb >= ntileM) return;                   // uniform early exit (pad blocks)
    const int row0  = rowb * PM;

    const int t      = threadIdx.x;
    const int lane15 = t & 15;
    const int quad   = (t >> 4) & 3;
    const int wave   = t >> 6;
    const int wr     = (wave >> 1) * 64;          // row half (0/64)
    const int wc     = (wave & 1) * 128;          // col half (0/128)
    const int sl     = quad ^ (lane15 & 3);       // swizzled k-granule read slot

    if (t == 0) flag_s = 0;
    if (t < PM) {
        int i = row0 + t;
        sqi_s[t] = (i < N) ? sqf[i] : 0.f;
        thr_s[t] = __builtin_inff();
        cnt_s[t] = 0;
    }

    // register-resident running top-NC list for row (row0 + t), t < PM
    float ls[NC];
    int   li[NC];
#pragma unroll
    for (int m = 0; m < NC; ++m) { ls[m] = __builtin_inff(); li[m] = 0x7fffffff; }

    f32x4 acc[4][8];                              // [mt][nt] -- 128 VGPRs

    const unsigned char* Abase = Atiled + (size_t)rowb * 16 * 8192;

    for (int tile = split; tile < ntileN; tile += CSPLIT) {
        int col0 = tile * PN;
        const unsigned char* Bbase = Btiled + (size_t)tile * 16 * 16384;

        {   // sqj fill: all 256 threads cover the 256 columns
            int j = col0 + t;
            sqj_s[t] = (j < N) ? sqf[j] : __builtin_inff();
        }
        __syncthreads();   // sqj visible + prior selection's Bsc/Bid accesses done

#pragma unroll
        for (int mt = 0; mt < 4; ++mt)
#pragma unroll
            for (int nt = 0; nt < 8; ++nt)
                acc[mt][nt] = (f32x4){0.f, 0.f, 0.f, 0.f};

        // streamed DMA of one chunk: contiguous 8KB (A) + 16KB (B) blocks.
        // 6 DMA instrs/thread; consecutive lanes read consecutive 16B.
        auto STAGE = [&](int cc, int buf) {
            unsigned char* base = lds_raw + (size_t)buf * 24576;
            const unsigned char* sa = Abase + (size_t)cc * 8192;
            const unsigned char* sb = Bbase + (size_t)cc * 16384;
#pragma unroll
            for (int l = 0; l < 2; ++l) {         // A region: 512 granules
                int e = t + l * 256;
                __builtin_amdgcn_global_load_lds(
                    (const unsigned int*)(sa + (size_t)e * 16),
                    (unsigned int*)(base + (size_t)e * 16), 16, 0, 0);
            }
#pragma unroll
            for (int l = 0; l < 4; ++l) {         // B region: 1024 granules
                int e = t + l * 256;
                __builtin_amdgcn_global_load_lds(
                    (const unsigned int*)(sb + (size_t)e * 16),
                    (unsigned int*)(base + 8192 + (size_t)e * 16), 16, 0, 0);
            }
        };

        STAGE(0, 0);                               // prologue prefetch (6 units)
#pragma unroll 1
        for (int cc = 0; cc < 16; ++cc) {
            if (cc < 15) {
                STAGE(cc + 1, (cc + 1) & 1);             // +6 -> 12 outstanding
                __builtin_amdgcn_sched_barrier(0);
                asm volatile("s_waitcnt vmcnt(6)" ::: "memory");  // retire chunk cc
            } else {
                __builtin_amdgcn_sched_barrier(0);
                asm volatile("s_waitcnt vmcnt(0)" ::: "memory");
            }
            __builtin_amdgcn_s_barrier();          // all waves' chunk-cc parts landed
            __builtin_amdgcn_sched_barrier(0);

            const unsigned char* rb = lds_raw + (size_t)(cc & 1) * 24576;
            bf16x8 af[4], bfg[8];
#pragma unroll
            for (int mt = 0; mt < 4; ++mt)
                af[mt] = *(const bf16x8*)(rb + (size_t)(wr + mt * 16 + lane15) * 64 + sl * 16);
#pragma unroll
            for (int nt = 0; nt < 8; ++nt)
                bfg[nt] = *(const bf16x8*)(rb + 8192 + (size_t)(wc + nt * 16 + lane15) * 64 + sl * 16);
#pragma unroll
            for (int mt = 0; mt < 4; ++mt)
#pragma unroll
                for (int nt = 0; nt < 8; ++nt)
                    acc[mt][nt] = __builtin_amdgcn_mfma_f32_16x16x32_bf16(
                        af[mt], bfg[nt], acc[mt][nt], 0, 0, 0);
            __builtin_amdgcn_sched_barrier(0);
            __builtin_amdgcn_s_barrier();          // reads done before buf re-staged
        }

        // epilogue: scores in place  s = (sq_i - 2g) + sq_j
#pragma unroll
        for (int mt = 0; mt < 4; ++mt)
#pragma unroll
            for (int nt = 0; nt < 8; ++nt)
#pragma unroll
                for (int reg = 0; reg < 4; ++reg) {
                    int rl = wr + mt * 16 + quad * 4 + reg;
                    int cl = wc + nt * 16 + lane15;
                    float g = acc[mt][nt][reg];
                    acc[mt][nt][reg] = (sqi_s[rl] - 2.f * g) + sqj_s[cl];
                }
        __syncthreads();   // all k-loops done before pushes touch the alias

        // merge helper: drain this row's push buffer into the register list
        auto MERGE = [&]() {
            if (t < PM) {
                int c = cnt_s[t];
                if (c > PBUF) c = PBUF;
                cnt_s[t] = 0;
                for (int m0 = 0; m0 < c; m0 += 4) {
                    float4 s4 = *(const float4*)&Bsc[t][m0];
                    int4   j4 = *(const int4*)&Bid[t][m0];
#pragma unroll
                    for (int e = 0; e < 4; ++e) {
                        if (m0 + e >= c) break;
                        float sv = (e == 0) ? s4.x : (e == 1) ? s4.y : (e == 2) ? s4.z : s4.w;
                        int   j  = (e == 0) ? j4.x : (e == 1) ? j4.y : (e == 2) ? j4.z : j4.w;
                        if (sv < ls[NC - 1] || (sv == ls[NC - 1] && j < li[NC - 1])) {
                            float cs = sv; int cj = j;
#pragma unroll
                            for (int p = 0; p < NC; ++p) {
                                bool lt = (cs < ls[p]) || (cs == ls[p] && cj < li[p]);
                                float ts = ls[p]; int tj = li[p];
                                if (lt) { ls[p] = cs; li[p] = cj; cs = ts; cj = tj; }
                            }
                        }
                    }
                }
                thr_s[t] = ls[NC - 1];
            }
        };

        bool tile_edge = (col0 + PN > N);
        unsigned long long done0 = 0ull, done1 = 0ull;

        if (tile == split) {
            // ---- seed round (first tile only; thr is inf): each thread
            // pushes only its per-row minimum -> 32 pushes/row = PBUF. ----
#pragma unroll
            for (int mt = 0; mt < 4; ++mt)
#pragma unroll
                for (int reg = 0; reg < 4; ++reg) {
                    int rl = wr + mt * 16 + quad * 4 + reg;
                    float mn = __builtin_inff(); int bn = -1;
#pragma unroll
                    for (int nt = 0; nt < 8; ++nt) {
                        float sv = acc[mt][nt][reg];
                        int   j  = col0 + wc + nt * 16 + lane15;
                        if (j < N && sv < mn) { mn = sv; bn = nt; }
                    }
                    if (bn >= 0) {
                        int pos = atomicAdd(&cnt_s[rl], 1);
                        if (pos < PBUF) {
                            Bsc[rl][pos] = mn;
                            Bid[rl][pos] = col0 + wc + bn * 16 + lane15;
                            unsigned long long bit =
                                1ull << (mt * 16 + (bn & 3) * 4 + reg);
                            if (bn < 4) done0 |= bit; else done1 |= bit;
                        }
                    } else {
                        // all 8 cols OOB -> whole group done in both masks
                        unsigned long long gb = (0x1111ull << reg) << (mt * 16);
                        done0 |= gb; done1 |= gb;
                    }
                }
            __syncthreads();             // seed pushes visible
            MERGE();                     // thr becomes ~40th-smallest of row
            __syncthreads();             // thr/cnt reset visible
        }

        // push/merge rounds: R5 protocol, two 64-bit done masks (nt halves)
        for (;;) {
#pragma unroll
            for (int hn = 0; hn < 2; ++hn) {
#pragma unroll
                for (int mt = 0; mt < 4; ++mt)
#pragma unroll
                    for (int reg = 0; reg < 4; ++reg) {
                        const unsigned long long gb =
                            (0x1111ull << reg) << (mt * 16);
                        unsigned long long dn = hn ? done1 : done0;
                        int rl = wr + mt * 16 + quad * 4 + reg;
                        float th = thr_s[rl];
                        float gmin = fminf(
                            fminf(acc[mt][hn * 4 + 0][reg], acc[mt][hn * 4 + 1][reg]),
                            fminf(acc[mt][hn * 4 + 2][reg], acc[mt][hn * 4 + 3][reg]));
                        if (!tile_edge && gmin > th) {
                            if (hn) done1 |= gb; else done0 |= gb;
                            continue;
                        }
                        if ((dn & gb) == gb) continue;
#pragma unroll
                        for (int u = 0; u < 4; ++u) {
                            const unsigned long long bit = 1ull << (mt * 16 + u * 4 + reg);
                            if (!(dn & bit)) {
                                float sv = acc[mt][hn * 4 + u][reg];
                                int   j  = col0 + wc + (hn * 4 + u) * 16 + lane15;
                                bool ok = false;
                                if (j < N && sv <= th) {
                                    int pos = atomicAdd(&cnt_s[rl], 1);
                                    if (pos < PBUF) {
                                        Bsc[rl][pos] = sv;
                                        Bid[rl][pos] = j;
                                        ok = true;
                                    }
                                } else {
                                    ok = true;
                                }
                                if (ok) { if (hn) done1 |= bit; else done0 |= bit; }
                            }
                        }
                    }
            }
            if (done0 != ~0ull || done1 != ~0ull) flag_s = 1;
            __syncthreads();                 // B1
            MERGE();
            __syncthreads();                 // B2
            int go = flag_s;
            __syncthreads();                 // B3
            if (t == 0) flag_s = 0;
            __syncthreads();                 // B4
            if (!go) break;
        }
    }
    // write this split's candidates (index + fp32 score) straight from registers
    if (t < PM) {
        int i = row0 + t;
        if (i < N) {
#pragma unroll
            for (int m = 0; m < NC; ++m) {
                cand [(size_t)i * NCTOT + split * NC + m] = li[m];
                cands[(size_t)i * NCTOT + split * NC + m] = ls[m];
            }
        }
    }
}

// ---------------- Kernel D: pruned exact fp64 rescore + top-k (R14 verbatim) ----------------
__global__ __launch_bounds__(256) void rescore_topk(
    const float* __restrict__ x, const double* __restrict__ w,
    const double* __restrict__ sq, const int* __restrict__ cand,
    const float* __restrict__ cands, int* __restrict__ out, int N, int k)
{
    __shared__ float Ssc[4][NCTOT];
    int lane = threadIdx.x & 63;
    int wid  = threadIdx.x >> 6;
    int i = blockIdx.x * 4 + wid;
    if (i >= N) return;

    size_t base = (size_t)i * NCTOT;
    Ssc[wid][lane] = cands[base + lane];
    if (lane < NCTOT - 64) Ssc[wid][64 + lane] = cands[base + 64 + lane];

    // 9th-smallest via pivot counting: pivots cover all 72 slots
    float p0 = Ssc[wid][lane];
    float p1 = Ssc[wid][64 + (lane & 7)];
    int c0 = 0, c1 = 0;
    for (int m = 0; m < NCTOT; ++m) {
        float s = Ssc[wid][m];
        c0 += (s <= p0); c1 += (s <= p1);
    }
    float best = __builtin_inff();
    if (c0 >= k) best = p0;
    if (c1 >= k && p1 < best) best = p1;
#pragma unroll
    for (int off = 32; off > 0; off >>= 1)
        best = fminf(best, __shfl_xor(best, off, 64));
    float cut = best + RS_MARGIN;

    double aw[8];
#pragma unroll
    for (int c = 0; c < 8; ++c) {
        int d = lane + 64 * c;
        aw[c] = (double)x[(size_t)i * DD + d] * w[d];
    }
    double sqi = sq[i];

    double bs[KOUTMAX];
    int    bj[KOUTMAX];
    for (int r = 0; r < k; ++r) { bs[r] = __builtin_inf(); bj[r] = 0x7fffffff; }

    int pend = -1;                    // wave-uniform pending candidate index j
    for (int m = 0; m <= NCTOT; ++m) {
        int j1cand = -1;
        if (m < NCTOT) {
            if (Ssc[wid][m] > cut) continue;          // wave-uniform skip
            j1cand = cand[base + m];
            if (pend < 0) { pend = j1cand; continue; } // buffer first of a pair
        } else if (pend < 0) {
            break;                                     // nothing left
        }
        int j0 = pend, j1 = j1cand;
        pend = -1;
        const float* q0 = &x[(size_t)j0 * DD + lane];
        const float* q1 = (j1 >= 0) ? &x[(size_t)j1 * DD + lane] : q0;
        float v0[8], v1[8];
#pragma unroll
        for (int c = 0; c < 8; ++c) v0[c] = q0[64 * c];
#pragma unroll
        for (int c = 0; c < 8; ++c) v1[c] = q1[64 * c];
        double d0 = 0.0, d1 = 0.0;
#pragma unroll
        for (int c = 0; c < 8; ++c) d0 = fma(aw[c], (double)v0[c], d0);
#pragma unroll
        for (int c = 0; c < 8; ++c) d1 = fma(aw[c], (double)v1[c], d1);
#pragma unroll
        for (int off = 32; off > 0; off >>= 1) {
            d0 += __shfl_xor(d0, off, 64);
            d1 += __shfl_xor(d1, off, 64);
        }
        double s0 = (sqi - 2.0 * d0) + sq[j0];
        double s1 = (j1 >= 0) ? (sqi - 2.0 * d1) + sq[j1] : __builtin_inf();
#pragma unroll 1
        for (int pick = 0; pick < 2; ++pick) {
            double sv = pick ? s1 : s0;
            int    j  = pick ? j1 : j0;
            if (j < 0) continue;
            if (sv < bs[k - 1] || (sv == bs[k - 1] && j < bj[k - 1])) {
                int pos = k - 1;
                while (pos > 0) {
                    double ps = bs[pos - 1]; int pj = bj[pos - 1];
                    if (!(sv < ps || (sv == ps && j < pj))) break;
                    bs[pos] = ps; bj[pos] = pj;
                    --pos;
                }
                bs[pos] = sv; bj[pos] = j;
            }
        }
    }
    if (lane == 0) {
        for (int r = 0; r < k; ++r) {
            out[(size_t)i * k + r]                 = bj[r];
            out[(size_t)N * k + (size_t)i * k + r] = i;
        }
    }
}

extern "C" void kernel_launch(void* const* d_in, const int* in_sizes, int n_in,
                              void* d_out, int out_size, void* d_ws, size_t ws_size,
                              hipStream_t stream) {
    const float* x = (const float*)d_in[0];
    int N = in_sizes[0] / DD;            // 10000
    int k = out_size / (2 * N);          // 9
    if (k > KOUTMAX) k = KOUTMAX;

    int ntileM = (N + PM - 1) / PM;      // 79 row-tiles of 128
    int ntileN = (N + PN - 1) / PN;      // 40 col-tiles of 256
    int NpadA  = ntileM * PM;            // 10112
    int NpadB  = ntileN * PN;            // 10240

    char* ws = (char*)d_ws;
    double*        partial = (double*)ws;                       // 400*512*8 = 1638400 B
    double*        rn      = (double*)(ws + 1638400);           // 4096 B
    double*        w       = (double*)(ws + 1642496);           // 4096 B
    double*        sq      = (double*)(ws + 1646592);           // 80000 B
    float*         sqf     = (float*) (ws + 1726592);           // 40000 B
    unsigned char* Atiled  = (unsigned char*)(ws + 1766592);    // 79*16*8192 = 10354688 B
    unsigned char* Btiled  = (unsigned char*)(ws + 12121280);   // 40*16*16384 = 10485760 B
    int*           cand    = (int*)   (ws + 22607040);          // N*72*4 = 2.88 MB
    float*         cands   = (float*) (ws + 25487040);          // N*72*4 = 2.88 MB -> end ~28.4 MB

    int rpb  = (N + NBLKA - 1) / NBLKA;
    int nblk = NBLKA;
    void* pre_args[] = { (void*)&x, (void*)&partial, (void*)&rn, (void*)&w,
                         (void*)&sq, (void*)&sqf, (void*)&Atiled, (void*)&Btiled,
                         (void*)&N, (void*)&rpb, (void*)&nblk,
                         (void*)&NpadA, (void*)&NpadB };
    hipLaunchCooperativeKernel((const void*)prekernel, dim3(NBLKA), dim3(256),
                               pre_args, 0, stream);

    int rows_per_xcd = (ntileM + 7) / 8; // 10
    int nblkc = 8 * rows_per_xcd * CSPLIT; // 480 (pad blocks exit early)
    hipLaunchKernelGGL(gemm_prefilter, dim3(nblkc), dim3(256), 0, stream,
                       Atiled, Btiled, sqf, cand, cands, N, ntileM, ntileN);

    hipLaunchKernelGGL(rescore_topk, dim3((N + 3) / 4), dim3(256), 0, stream,
                       x, w, sq, cand, cands, (int*)d_out, N, k);
}